// Round 21
// baseline (73.457 us; speedup 1.0000x reference)
//
#include <hip/hip_runtime.h>
#include <hip/hip_bf16.h>
#include <cstdint>

// LSTM cell, B=16384, IN=512, H=512 — fused 4-gate INT8 MFMA GEMM.
// Round 20: GEMM = r18 verbatim (proven: ring-3, vmcnt(3), 2 blocks/CU,
// XCD-grouped mapping, division-free epilogue). W-prep merged into ONE kernel
// (max+quantize from registers — W read once instead of twice, one fewer
// dispatch). r19's ring-2/3-block sync abandoned: post-timing race.

typedef __attribute__((ext_vector_type(4))) int   i32x4;
typedef __attribute__((ext_vector_type(4))) float f32x4;
typedef __attribute__((address_space(3))) char lds_char;

#define GLOAD_LDS16(gp, lp)                                                        \
    __builtin_amdgcn_global_load_lds(                                              \
        (const __attribute__((address_space(1))) void*)(gp),                       \
        (__attribute__((address_space(3))) void*)(lp), 16, 0, 0)

#define BAR()  asm volatile("s_barrier" ::: "memory")
#define VMW3() asm volatile("s_waitcnt vmcnt(3)" ::: "memory")
#define VMW0() asm volatile("s_waitcnt vmcnt(0)" ::: "memory")
#define LGK0() { asm volatile("s_waitcnt lgkmcnt(0)" ::: "memory");                \
                 __builtin_amdgcn_sched_barrier(0); }
#define DSR(dst, off)                                                              \
    asm volatile("ds_read_b128 %0, %1" : "=v"(dst) : "v"(lds3 + (off)))

#define RCP(x)  __builtin_amdgcn_rcpf(x)
#define EXP2(x) __builtin_amdgcn_exp2f(x)

__device__ __forceinline__ unsigned int pkq4(float a, float b, float c, float d,
                                             float qs) {
    int q0 = __float2int_rn(a * qs) & 255;
    int q1 = __float2int_rn(b * qs) & 255;
    int q2 = __float2int_rn(c * qs) & 255;
    int q3 = __float2int_rn(d * qs) & 255;
    return (unsigned)q0 | ((unsigned)q1 << 8) | ((unsigned)q2 << 16)
         | ((unsigned)q3 << 24);
}

// ---------------- prepass A: per-row max + quantize + swizzled layout ----------
__global__ __launch_bounds__(256) void conv_a_q(const float* __restrict__ x,
                                                const float* __restrict__ h,
                                                char* __restrict__ Aq,
                                                float* __restrict__ As) {
    const int lane = threadIdx.x & 63;
    const int r    = blockIdx.x * 4 + (threadIdx.x >> 6);   // grid 4096
    const int k0   = lane * 16;
    const float* src = (k0 < 512) ? (x + (size_t)r * 512 + k0)
                                  : (h + (size_t)r * 512 + (k0 - 512));
    const float4* s4 = reinterpret_cast<const float4*>(src);
    float4 v0 = s4[0], v1 = s4[1], v2 = s4[2], v3 = s4[3];

    float m = fabsf(v0.x);
    m = fmaxf(m, fabsf(v0.y)); m = fmaxf(m, fabsf(v0.z)); m = fmaxf(m, fabsf(v0.w));
    m = fmaxf(m, fabsf(v1.x)); m = fmaxf(m, fabsf(v1.y)); m = fmaxf(m, fabsf(v1.z));
    m = fmaxf(m, fabsf(v1.w)); m = fmaxf(m, fabsf(v2.x)); m = fmaxf(m, fabsf(v2.y));
    m = fmaxf(m, fabsf(v2.z)); m = fmaxf(m, fabsf(v2.w)); m = fmaxf(m, fabsf(v3.x));
    m = fmaxf(m, fabsf(v3.y)); m = fmaxf(m, fabsf(v3.z)); m = fmaxf(m, fabsf(v3.w));
    #pragma unroll
    for (int off = 1; off < 64; off <<= 1)
        m = fmaxf(m, __shfl_xor(m, off));
    m = fmaxf(m, 1e-20f);
    const float qs = 127.0f / m;
    if (lane == 0) As[r] = m * (1.0f / 127.0f);

    uint4 o;
    o.x = pkq4(v0.x, v0.y, v0.z, v0.w, qs);
    o.y = pkq4(v1.x, v1.y, v1.z, v1.w, qs);
    o.z = pkq4(v2.x, v2.y, v2.z, v2.w, qs);
    o.w = pkq4(v3.x, v3.y, v3.z, v3.w, qs);

    const int t     = lane >> 2;
    const int csrc  = lane & 3;
    const int mt    = r >> 8;
    const int rl    = r & 255;
    const int kcpos = csrc ^ ((rl >> 1) & 3);
    *reinterpret_cast<uint4*>(Aq + (((size_t)(mt * 16 + t)) << 14)
                                 + rl * 64 + kcpos * 16) = o;
}

// ---------------- prepass W: fused max + quantize (W read ONCE) ----------------
// One wave per (gate g, col n). Lane holds W_g[lane*16+u][n], u=0..15 — exactly
// one 16B Bq chunk (k0 = lane*16 = (lane>>2)*64 + (lane&3)*16). After the
// shfl max-reduce every lane has m; pack in-register and store.
__global__ __launch_bounds__(256) void conv_w_fused(const float* __restrict__ w0,
                                                    const float* __restrict__ w1,
                                                    const float* __restrict__ w2,
                                                    const float* __restrict__ w3,
                                                    float* __restrict__ Ws,
                                                    char* __restrict__ Bq) {
    const int lane = threadIdx.x & 63;
    const int idx  = blockIdx.x * 4 + (threadIdx.x >> 6);   // grid 512 -> 0..2047
    const int g    = idx >> 9;
    const int n    = idx & 511;
    const float* Wg = (g == 0) ? w0 : (g == 1) ? w1 : (g == 2) ? w2 : w3;

    float v[16];
    #pragma unroll
    for (int u = 0; u < 16; ++u)
        v[u] = Wg[(size_t)(lane * 16 + u) * 512 + n];

    float m = fabsf(v[0]);
    #pragma unroll
    for (int u = 1; u < 16; ++u) m = fmaxf(m, fabsf(v[u]));
    #pragma unroll
    for (int off = 1; off < 64; off <<= 1)
        m = fmaxf(m, __shfl_xor(m, off));
    m = fmaxf(m, 1e-20f);
    if (lane == 0) Ws[idx] = m * (1.0f / 127.0f);
    const float qs = 127.0f / m;

    uint4 o;
    o.x = pkq4(v[0],  v[1],  v[2],  v[3],  qs);
    o.y = pkq4(v[4],  v[5],  v[6],  v[7],  qs);
    o.z = pkq4(v[8],  v[9],  v[10], v[11], qs);
    o.w = pkq4(v[12], v[13], v[14], v[15], qs);

    const int nb    = n >> 5;
    const int col   = (g << 5) | (n & 31);
    const int t     = lane >> 2;
    const int kcpos = (lane & 3) ^ ((col >> 1) & 3);
    *reinterpret_cast<uint4*>(Bq + (size_t)(nb * 16 + t) * 8192
                                 + col * 64 + kcpos * 16) = o;
}

// ---------------- fused i8 GEMM: 256x128 tile, ring-3, 2 blocks/CU ----------------
__global__ __launch_bounds__(512, 4) void lstm_gemm8(
    const char* __restrict__ Aq, const char* __restrict__ Bq,
    const float* __restrict__ As, const float* __restrict__ Ws,
    const float* __restrict__ c_cur,
    const float* __restrict__ bi_p, const float* __restrict__ bf_p,
    const float* __restrict__ bo_p, const float* __restrict__ bc_p,
    float* __restrict__ h_out, float* __restrict__ c_out)
{
    extern __shared__ char smem[];
    lds_char* lds3 = (lds_char*)smem;
    const int tid  = threadIdx.x;
    const int lane = tid & 63;
    const int wid  = tid >> 6;    // 0..7
    const int wm   = wid >> 1;    // 0..3 (64-row group)
    const int wn   = wid & 1;     // 0..1 (16-h half)

    // XCD-grouped bijective mapping (r13, FETCH-verified)
    const int mt = (blockIdx.x & 7) * 8 + (blockIdx.x >> 7);
    const int nb = (blockIdx.x >> 3) & 15;

    const int ar    = lane & 15;
    const int swz   = ((lane >> 4) ^ ((ar >> 1) & 3)) << 4;
    const int aoffb = ar * 64 + swz;
    const int boffb = 16384 + (wn * 16 + ar) * 64 + swz;
    const int swl   = wid * 1024;

    const char* AqB = Aq + (((size_t)mt * 16) << 14) + (size_t)tid * 16;
    const char* BqB = Bq + (((size_t)nb * 16) << 13) + (size_t)tid * 16;

#define STAGE(t, bb) {                                                  \
        const char* ga_ = AqB + (((size_t)(t)) << 14);                  \
        const char* gb_ = BqB + (((size_t)(t)) << 13);                  \
        GLOAD_LDS16(ga_,        smem + (bb) + swl);                     \
        GLOAD_LDS16(ga_ + 8192, smem + (bb) + 8192 + swl);              \
        GLOAD_LDS16(gb_,        smem + (bb) + 16384 + swl); }

    i32x4 acc[4][4];   // [gate][m-frag]
    #pragma unroll
    for (int g = 0; g < 4; ++g)
        #pragma unroll
        for (int m = 0; m < 4; ++m)
            acc[g][m] = (i32x4){0, 0, 0, 0};

    i32x4 aFr[4], bFr[4];

    // prologue: stage K-tiles 0,1 into bufs 0,1 (6 loads in flight)
    STAGE(0, 0);
    STAGE(1, 24576);

    #pragma unroll 1
    for (int j = 0; j < 16; ++j) {
        const int buf  = (j % 3) * 24576;
        const int bufN = ((j + 2) % 3) * 24576;

        if (j < 15) { VMW3(); } else { VMW0(); }
        BAR();
        if (j < 14) STAGE(j + 2, bufN);

        #pragma unroll
        for (int mi = 0; mi < 4; ++mi)
            DSR(aFr[mi], buf + wm * 4096 + mi * 1024 + aoffb);
        #pragma unroll
        for (int g = 0; g < 4; ++g)
            DSR(bFr[g], buf + g * 2048 + boffb);

        LGK0();
        __builtin_amdgcn_s_setprio(1);
        #pragma unroll
        for (int g = 0; g < 4; ++g)
            #pragma unroll
            for (int m = 0; m < 4; ++m)
                acc[g][m] = __builtin_amdgcn_mfma_i32_16x16x64_i8(
                    aFr[m], bFr[g], acc[g][m], 0, 0, 0);
        __builtin_amdgcn_s_setprio(0);
    }

    // ---- fused LSTM epilogue: division-free, folded-constant form ----
    const float L2E = 1.442695041f;
    const int r4   = (lane >> 4) * 4;
    const int hcol = nb * 32 + wn * 16 + ar;
    const float swiL = -L2E * Ws[hcol];
    const float swfL = -L2E * Ws[512 + hcol];
    const float swoL = -L2E * Ws[1024 + hcol];
    const float swcL = -2.f * L2E * Ws[1536 + hcol];
    const float biL  = -L2E * bi_p[hcol];
    const float bfL  = -L2E * bf_p[hcol];
    const float boL  = -L2E * bo_p[hcol];
    const float bcL  = -2.f * L2E * bc_p[hcol];
    #pragma unroll
    for (int m = 0; m < 4; ++m) {
        const int rowb = mt * 256 + wm * 64 + m * 16 + r4;
        const float4 sa = *reinterpret_cast<const float4*>(As + rowb);
        const float sar[4] = {sa.x, sa.y, sa.z, sa.w};
        #pragma unroll
        for (int rr = 0; rr < 4; ++rr) {
            const size_t o = (size_t)(rowb + rr) * 512 + hcol;
            const float s = sar[rr];
            float ti = fmaf((float)acc[0][m][rr] * swiL, s, biL);
            float tf = fmaf((float)acc[1][m][rr] * swfL, s, bfL);
            float to = fmaf((float)acc[2][m][rr] * swoL, s, boL);
            float tc = fmaf((float)acc[3][m][rr] * swcL, s, bcL);
            float is = RCP(1.f + EXP2(ti));
            float fs = RCP(1.f + EXP2(tf));
            float os = RCP(1.f + EXP2(to));
            float ct = fmaf(2.f, RCP(1.f + EXP2(tc)), -1.f);
            float cn = fmaf(fs, c_cur[o], is * ct);
            float th = fmaf(2.f, RCP(1.f + EXP2(cn * (-2.f * L2E))), -1.f);
            h_out[o] = os * th;
            c_out[o] = cn;
        }
    }
#undef STAGE
}

extern "C" void kernel_launch(void* const* d_in, const int* in_sizes, int n_in,
                              void* d_out, int out_size, void* d_ws, size_t ws_size,
                              hipStream_t stream) {
    const float* x   = (const float*)d_in[0];
    const float* h   = (const float*)d_in[1];
    const float* c   = (const float*)d_in[2];
    const float* W_i = (const float*)d_in[3];
    const float* b_i = (const float*)d_in[4];
    const float* W_f = (const float*)d_in[5];
    const float* b_f = (const float*)d_in[6];
    const float* W_o = (const float*)d_in[7];
    const float* b_o = (const float*)d_in[8];
    const float* W_c = (const float*)d_in[9];
    const float* b_c = (const float*)d_in[10];

    char*  Aq = (char*)d_ws;                             // 16,777,216 B
    char*  Bq = (char*)d_ws + 16777216;                  //  2,097,152 B
    float* As = (float*)((char*)d_ws + 18874368);        //     65,536 B
    float* Ws = (float*)((char*)d_ws + 18939904);        //      8,192 B

    float* h_out = (float*)d_out;
    float* c_out = h_out + (size_t)16384 * 512;

    (void)hipFuncSetAttribute(reinterpret_cast<const void*>(lstm_gemm8),
                              hipFuncAttributeMaxDynamicSharedMemorySize, 73728);

    conv_a_q<<<4096, 256, 0, stream>>>(x, h, Aq, As);
    conv_w_fused<<<512, 256, 0, stream>>>(W_i, W_f, W_o, W_c, Ws, Bq);
    lstm_gemm8<<<1024, 512, 73728, stream>>>(Aq, Bq, As, Ws, c,
                                             b_i, b_f, b_o, b_c, h_out, c_out);
}